// Round 2
// baseline (2928.783 us; speedup 1.0000x reference)
//
#include <hip/hip_runtime.h>
#include <hip/hip_bf16.h>

// SocialLSTM forward, MI355X gfx950.
// Dual-dtype: float inputs may be bf16 or f32; detected at runtime from W_soc.
// ws layout (bytes):
//   h_ws  f32[1024*64]   @ 0
//   c_ws  f32[1024*64]   @ 262144
//   r_ws  f32[1024*64]   @ 524288
//   epre  f32[1024*256]  @ 786432
//   Wt    bf16[256*4096] @ 1835008   (W_soc transposed, [n][k])
//   Hbuf  bf16[1024*3520]@ 3932160   (55 reachable cells * 64 hid per row)
//   flag  int32          @ 11141120  (0 = bf16 inputs, 1 = f32 inputs)

typedef short bf16x8 __attribute__((ext_vector_type(8)));
typedef float f32x4 __attribute__((ext_vector_type(4)));

__device__ __forceinline__ float u2f(unsigned short u) {
    union { unsigned int i; float f; } v; v.i = ((unsigned int)u) << 16; return v.f;
}
__device__ __forceinline__ unsigned short f2b(float f) {
    __hip_bfloat16 hb = __float2bfloat16(f);
    return *(unsigned short*)&hb;
}
__device__ __forceinline__ float ldin(const void* p, int idx, int isf32) {
    return isf32 ? ((const float*)p)[idx] : u2f(((const unsigned short*)p)[idx]);
}
__device__ __forceinline__ int get_tpred(const int* p) {
    int v = p[0];
    if (v >= 0 && v <= 64) return v;
    float f = ((const float*)p)[0];
    if (f >= 0.f && f <= 64.f) return (int)f;
    float g = u2f(((const unsigned short*)p)[0]);
    if (g >= 0.f && g <= 64.f) return (int)g;
    return 31;
}

// ---------------- dtype detector: bf16-decode W_soc, look for huge/NaN -----
__global__ __launch_bounds__(256) void k_detect(const void* __restrict__ Wsoc,
                                                int* __restrict__ flag) {
    __shared__ int f;
    int tid = threadIdx.x;
    if (tid == 0) f = 0;
    __syncthreads();
    const unsigned short* p = (const unsigned short*)Wsoc;
    #pragma unroll
    for (int k = 0; k < 4; k++) {
        float v = u2f(p[tid * 4 + k]);
        if (!(v == v) || fabsf(v) > 1e20f) f = 1;   // same-address LDS write, benign
    }
    __syncthreads();
    if (tid == 0) flag[0] = f;
}

// ---------------- one-time: W_soc (4096x256) -> Wt bf16 (256x4096) ---------
__global__ __launch_bounds__(256) void k_transpose(const void* __restrict__ Wsoc,
                                                   unsigned short* __restrict__ Wt,
                                                   const int* __restrict__ flag) {
    __shared__ __align__(16) unsigned short tile[32 * 264];
    int isf32 = flag[0];
    int b = blockIdx.x, tid = threadIdx.x;
    int k0 = b * 32;
    if (isf32) {
        const float* W = (const float*)Wsoc;
        #pragma unroll
        for (int p = 0; p < 4; p++) {
            int kk = (tid >> 5) + p * 8;
            int n8 = (tid & 31) * 8;
            #pragma unroll
            for (int q = 0; q < 8; q++)
                tile[kk * 264 + n8 + q] = f2b(W[(k0 + kk) * 256 + n8 + q]);
        }
    } else {
        const unsigned short* W = (const unsigned short*)Wsoc;
        #pragma unroll
        for (int p = 0; p < 4; p++) {
            int kk = (tid >> 5) + p * 8;
            int n8 = (tid & 31) * 8;
            *(uint4*)&tile[kk * 264 + n8] = *(const uint4*)(W + (k0 + kk) * 256 + n8);
        }
    }
    __syncthreads();
    int n = tid;
    unsigned int packed[16];
    #pragma unroll
    for (int q = 0; q < 16; q++) {
        unsigned int lo = tile[(2 * q) * 264 + n];
        unsigned int hi = tile[(2 * q + 1) * 264 + n];
        packed[q] = lo | (hi << 16);
    }
    uint4* dst = (uint4*)(Wt + (long)n * 4096 + k0);
    #pragma unroll
    for (int p = 0; p < 4; p++)
        dst[p] = make_uint4(packed[4*p], packed[4*p+1], packed[4*p+2], packed[4*p+3]);
}

// ---------------- one-time: zero d_out (dtype-sized), h0/c0 -> f32 ---------
__global__ __launch_bounds__(256) void k_init(void* __restrict__ out,
                                              const void* __restrict__ hin,
                                              const void* __restrict__ cin,
                                              float* __restrict__ h_ws,
                                              float* __restrict__ c_ws,
                                              const int* __restrict__ flag) {
    int isf32 = flag[0];
    int b = blockIdx.x, tid = threadIdx.x;
    if (b < 16) {
        uint4 z = make_uint4(0u, 0u, 0u, 0u);
        uint4* p = (uint4*)out;
        int n16 = isf32 ? 16384 : 8192;          // 65536 elems * 4 or 2 bytes / 16
        for (int idx = b * 256 + tid; idx < n16; idx += 4096) p[idx] = z;
    } else {
        int sb = b - 16;
        const void* src = (sb < 16) ? hin : cin;
        float* dst = (sb < 16) ? h_ws : c_ws;
        sb &= 15;
        int base = (sb * 256 + tid) * 16;
        #pragma unroll
        for (int p = 0; p < 16; p++) dst[base + p] = ldin(src, base + p, isf32);
    }
}

// ---------------- per step: social pooling -> Hbuf, epre=b_soc, r ----------
__global__ __launch_bounds__(256) void k_pool(const void* __restrict__ X,
                                              const int* __restrict__ masks,
                                              const void* __restrict__ bsoc,
                                              const void* __restrict__ Wemb,
                                              const void* __restrict__ bemb,
                                              const int* __restrict__ Tpred,
                                              const int* __restrict__ flag,
                                              const float* __restrict__ h_ws,
                                              float* __restrict__ r_ws,
                                              float* __restrict__ epre,
                                              unsigned short* __restrict__ Hbuf,
                                              int t) {
    if (t > get_tpred(Tpred)) return;
    int isf32 = flag[0];
    int i = blockIdx.x, tid = threadIdx.x;
    __shared__ __align__(16) float H4[4][3584];   // 55 cells * 64 hid, padded
    __shared__ unsigned char code[1024];
    __shared__ float cis[2];
    int mi = masks[t * 1024 + i];
    if (tid == 0) {
        cis[0] = ldin(X, (t * 1024 + i) * 4 + 2, isf32);
        cis[1] = ldin(X, (t * 1024 + i) * 4 + 3, isf32);
    }
    epre[i * 256 + tid] = ldin(bsoc, tid, isf32);
    {
        float4 z4 = make_float4(0.f, 0.f, 0.f, 0.f);
        float4* hp = (float4*)&H4[0][0];          // 14336 f32 = 3584 float4
        #pragma unroll
        for (int p = 0; p < 14; p++) hp[tid + p * 256] = z4;
    }
    __syncthreads();
    float cix = cis[0], ciy = cis[1];
    if (tid < 64) {
        float v = ldin(Wemb, tid, isf32) * cix + ldin(Wemb, 64 + tid, isf32) * ciy
                + ldin(bemb, tid, isf32);
        r_ws[i * 64 + tid] = fmaxf(v, 0.f);
    }
    if (mi != 0) {
        #pragma unroll
        for (int p = 0; p < 4; p++) {
            int j = tid + p * 256;
            unsigned char cc = 0xFF;
            if (j != i && masks[t * 1024 + j] != 0) {
                float dx = ldin(X, (t * 1024 + j) * 4 + 2, isf32) - cix;
                float dy = ldin(X, (t * 1024 + j) * 4 + 3, isf32) - ciy;
                int g0 = (int)dx, g1 = (int)dy;   // trunc toward zero, matches jnp.trunc
                if (g0 >= -3 && g0 <= 3 && g1 >= -3 && g1 <= 3)
                    cc = (unsigned char)(((g0 + 4) * 8 + (g1 + 4)) - 9);  // 9..63 -> 0..54
            }
            code[j] = cc;
        }
    }
    __syncthreads();
    if (mi != 0) {
        int w = tid >> 6, lane = tid & 63;
        float* Hw = H4[w];
        int jbase = w << 8;
        for (int jj = 0; jj < 256; jj++) {
            int cc = code[jbase + jj];            // wave-uniform LDS broadcast
            if (cc != 0xFF) {
                float hv = h_ws[(jbase + jj) * 64 + lane];
                Hw[cc * 64 + lane] += hv;         // lane-exclusive column: no races
            }
        }
    }
    __syncthreads();
    for (int idx = tid; idx < 3520; idx += 256) {
        float s = H4[0][idx] + H4[1][idx] + H4[2][idx] + H4[3][idx];
        Hbuf[(long)i * 3520 + idx] = f2b(s);
    }
}

// ---------------- per step: epre += H @ W_soc (MFMA, K-split atomics) ------
__global__ __launch_bounds__(256) void k_gemm(const unsigned short* __restrict__ Hbuf,
                                              const unsigned short* __restrict__ Wt,
                                              const int* __restrict__ Tpred,
                                              float* __restrict__ epre,
                                              int t) {
    if (t > get_tpred(Tpred)) return;
    int bid = blockIdx.x, tid = threadIdx.x;
    int s = bid & 15, rb = bid >> 4;
    int row0 = rb * 64;
    int m0 = 3 * s, m1 = (s == 15) ? 49 : (3 * s + 3);   // 49 used cells
    __shared__ __align__(16) short Asm[64 * 72];   // 64 rows x 64 k, stride 72
    __shared__ __align__(16) short Bsm[256 * 72];  // 256 n x 64 k, stride 72
    int w = tid >> 6, lane = tid & 63;
    int wrow = (w & 1) * 32, wcol = (w >> 1) * 128;
    int mrow = lane & 15, q = lane >> 4;
    f32x4 acc[2][8];
    f32x4 zz = {0.f, 0.f, 0.f, 0.f};
    #pragma unroll
    for (int a = 0; a < 2; a++)
        #pragma unroll
        for (int b = 0; b < 8; b++) acc[a][b] = zz;
    for (int m = m0; m < m1; m++) {
        int ncell = ((m / 7) << 3) + (m % 7);     // used cell index 0..54
        __syncthreads();
        {
            int row = tid >> 2;
            #pragma unroll
            for (int p = 0; p < 2; p++) {
                int seg = (tid & 3) + (p << 2);
                *(uint4*)&Asm[row * 72 + seg * 8] =
                    *(const uint4*)(Hbuf + (long)(row0 + row) * 3520 + ncell * 64 + seg * 8);
            }
            #pragma unroll
            for (int p = 0; p < 8; p++) {
                *(uint4*)&Bsm[tid * 72 + p * 8] =
                    *(const uint4*)(Wt + (long)tid * 4096 + (ncell + 9) * 64 + p * 8);
            }
        }
        __syncthreads();
        #pragma unroll
        for (int kc = 0; kc < 2; kc++) {
            bf16x8 a0 = *(bf16x8*)&Asm[(wrow +      mrow) * 72 + kc * 32 + q * 8];
            bf16x8 a1 = *(bf16x8*)&Asm[(wrow + 16 + mrow) * 72 + kc * 32 + q * 8];
            #pragma unroll
            for (int ct = 0; ct < 8; ct++) {
                bf16x8 bv = *(bf16x8*)&Bsm[(wcol + ct * 16 + mrow) * 72 + kc * 32 + q * 8];
                acc[0][ct] = __builtin_amdgcn_mfma_f32_16x16x32_bf16(a0, bv, acc[0][ct], 0, 0, 0);
                acc[1][ct] = __builtin_amdgcn_mfma_f32_16x16x32_bf16(a1, bv, acc[1][ct], 0, 0, 0);
            }
        }
    }
    // C/D layout: col = lane&15, row = (lane>>4)*4 + reg
    #pragma unroll
    for (int rt = 0; rt < 2; rt++)
        #pragma unroll
        for (int ct = 0; ct < 8; ct++)
            #pragma unroll
            for (int r = 0; r < 4; r++) {
                int grow = row0 + wrow + rt * 16 + q * 4 + r;
                int gcol = wcol + ct * 16 + mrow;
                atomicAdd(&epre[grow * 256 + gcol], acc[rt][ct][r]);
            }
}

// ---------------- per step: gates, LSTM cell, output -----------------------
__global__ __launch_bounds__(256) void k_cell(const int* __restrict__ masks,
                                              const void* __restrict__ Y,
                                              const void* __restrict__ Wih,
                                              const void* __restrict__ bih,
                                              const void* __restrict__ Whh,
                                              const void* __restrict__ bhh,
                                              const void* __restrict__ Wout,
                                              const void* __restrict__ bout,
                                              const int* __restrict__ Tpred,
                                              const int* __restrict__ flag,
                                              float* __restrict__ h_ws,
                                              float* __restrict__ c_ws,
                                              const float* __restrict__ r_ws,
                                              const float* __restrict__ epre,
                                              void* __restrict__ out,
                                              int t) {
    if (t > get_tpred(Tpred)) return;
    int isf32 = flag[0];
    int tid = threadIdx.x;
    int half = tid >> 7;
    int row = blockIdx.x * 2 + half;
    int tt = tid & 127;
    int s = tt >> 6, lane = tt & 63;
    __shared__ float z[2][384];
    __shared__ float gacc[2][256];
    for (int idx = tt; idx < 384; idx += 128) {
        float v;
        if (idx < 64)       v = r_ws[row * 64 + idx];
        else if (idx < 320) v = fmaxf(epre[row * 256 + (idx - 64)], 0.f);
        else                v = h_ws[row * 64 + (idx - 320)];
        z[half][idx] = v;
    }
    __syncthreads();
    float a0 = 0.f, a1 = 0.f, a2 = 0.f, a3 = 0.f;
    int kk0 = s * 192;
    if (isf32) {
        const float* WihF = (const float*)Wih;
        const float* WhhF = (const float*)Whh;
        for (int kk = kk0; kk < kk0 + 192; kk++) {
            float zv = z[half][kk];
            const float* Wr = (kk < 320) ? (WihF + (long)kk * 256)
                                         : (WhhF + (long)(kk - 320) * 256);
            a0 += zv * Wr[lane];
            a1 += zv * Wr[64 + lane];
            a2 += zv * Wr[128 + lane];
            a3 += zv * Wr[192 + lane];
        }
    } else {
        const unsigned short* WihB = (const unsigned short*)Wih;
        const unsigned short* WhhB = (const unsigned short*)Whh;
        for (int kk = kk0; kk < kk0 + 192; kk++) {
            float zv = z[half][kk];
            const unsigned short* Wr = (kk < 320) ? (WihB + (long)kk * 256)
                                                  : (WhhB + (long)(kk - 320) * 256);
            a0 += zv * u2f(Wr[lane]);
            a1 += zv * u2f(Wr[64 + lane]);
            a2 += zv * u2f(Wr[128 + lane]);
            a3 += zv * u2f(Wr[192 + lane]);
        }
    }
    if (s == 0) {
        gacc[half][lane] = a0; gacc[half][64 + lane] = a1;
        gacc[half][128 + lane] = a2; gacc[half][192 + lane] = a3;
    }
    __syncthreads();
    if (s == 1) {
        float gi = a0 + gacc[half][lane]       + ldin(bih, lane, isf32)       + ldin(bhh, lane, isf32);
        float gf = a1 + gacc[half][64 + lane]  + ldin(bih, 64 + lane, isf32)  + ldin(bhh, 64 + lane, isf32);
        float gg = a2 + gacc[half][128 + lane] + ldin(bih, 128 + lane, isf32) + ldin(bhh, 128 + lane, isf32);
        float go = a3 + gacc[half][192 + lane] + ldin(bih, 192 + lane, isf32) + ldin(bhh, 192 + lane, isf32);
        float c  = c_ws[row * 64 + lane];
        float si = 1.f / (1.f + __expf(-gi));
        float sf = 1.f / (1.f + __expf(-gf));
        float so = 1.f / (1.f + __expf(-go));
        float cn = sf * c + si * tanhf(gg);
        float hn = so * tanhf(cn);
        c_ws[row * 64 + lane] = cn;
        h_ws[row * 64 + lane] = hn;
        float p0 = hn * ldin(Wout, lane * 2 + 0, isf32);
        float p1 = hn * ldin(Wout, lane * 2 + 1, isf32);
        #pragma unroll
        for (int o = 32; o >= 1; o >>= 1) {
            p0 += __shfl_xor(p0, o);
            p1 += __shfl_xor(p1, o);
        }
        if (lane == 0) {
            int m = masks[t * 1024 + row];
            float o0 = 0.f, o1 = 0.f;
            if (m != 0) {
                bool appear = (t > 3) && (masks[(t - 3) * 1024 + row] == 0);
                if (appear) {
                    o0 = ldin(Y, (t * 1024 + row) * 2 + 0, isf32);
                    o1 = ldin(Y, (t * 1024 + row) * 2 + 1, isf32);
                } else {
                    o0 = p0 + ldin(bout, 0, isf32);
                    o1 = p1 + ldin(bout, 1, isf32);
                }
            }
            if (!(o0 == o0)) o0 = 0.f;            // sanitize: finite diagnostics
            if (!(o1 == o1)) o1 = 0.f;
            int ofs = (t * 1024 + row) * 2;
            if (isf32) {
                ((float*)out)[ofs + 0] = o0;
                ((float*)out)[ofs + 1] = o1;
            } else {
                ((unsigned short*)out)[ofs + 0] = f2b(o0);
                ((unsigned short*)out)[ofs + 1] = f2b(o1);
            }
        }
    }
}

extern "C" void kernel_launch(void* const* d_in, const int* in_sizes, int n_in,
                              void* d_out, int out_size, void* d_ws, size_t ws_size,
                              hipStream_t stream) {
    (void)in_sizes; (void)n_in; (void)out_size; (void)ws_size;
    const void* X     = d_in[0];
    const int*  masks = (const int*)d_in[1];
    const void* h0    = d_in[2];
    const void* c0    = d_in[3];
    const void* Y     = d_in[4];
    // d_in[5] = T_obs (unused by reference)
    const int*  Tpred = (const int*)d_in[6];
    const void* Wemb  = d_in[7];
    const void* bemb  = d_in[8];
    const void* Wsoc  = d_in[9];
    const void* bsoc  = d_in[10];
    const void* Wih   = d_in[11];
    const void* bih   = d_in[12];
    const void* Whh   = d_in[13];
    const void* bhh   = d_in[14];
    const void* Wout  = d_in[15];
    const void* bout  = d_in[16];

    char* ws = (char*)d_ws;
    float*          h_ws = (float*)(ws + 0);
    float*          c_ws = (float*)(ws + 262144);
    float*          r_ws = (float*)(ws + 524288);
    float*          epre = (float*)(ws + 786432);
    unsigned short* Wt   = (unsigned short*)(ws + 1835008);
    unsigned short* Hbuf = (unsigned short*)(ws + 3932160);
    int*            flag = (int*)(ws + 11141120);

    k_detect<<<1, 256, 0, stream>>>(Wsoc, flag);
    k_transpose<<<128, 256, 0, stream>>>(Wsoc, Wt, flag);
    k_init<<<48, 256, 0, stream>>>(d_out, h0, c0, h_ws, c_ws, flag);
    for (int t = 0; t < 32; t++) {
        k_pool<<<1024, 256, 0, stream>>>(X, masks, bsoc, Wemb, bemb, Tpred, flag,
                                         h_ws, r_ws, epre, Hbuf, t);
        k_gemm<<<256, 256, 0, stream>>>(Hbuf, Wt, Tpred, epre, t);
        k_cell<<<512, 256, 0, stream>>>(masks, Y, Wih, bih, Whh, bhh, Wout, bout,
                                        Tpred, flag, h_ws, c_ws, r_ws, epre, d_out, t);
    }
}

// Round 3
// 1728.978 us; speedup vs baseline: 1.6939x; 1.6939x over previous
//
#include <hip/hip_runtime.h>
#include <hip/hip_bf16.h>

// SocialLSTM forward, MI355X gfx950.
// Dual-dtype: float inputs may be bf16 or f32; detected at runtime from W_soc.
// ws layout (bytes):
//   h_ws  f32[1024*64]   @ 0
//   c_ws  f32[1024*64]   @ 262144
//   r_ws  f32[1024*64]   @ 524288
//   epre  f32[1024*256]  @ 786432
//   Wt    bf16[256*4096] @ 1835008   (W_soc transposed, [n][k])
//   Hbuf  bf16[1024*3136]@ 3932160   (49 reachable cells * 64 hid per row)
//   flag  int32          @ 11141120  (0 = bf16 inputs, 1 = f32 inputs)

typedef short bf16x8 __attribute__((ext_vector_type(8)));
typedef float f32x4 __attribute__((ext_vector_type(4)));

__device__ __forceinline__ float u2f(unsigned short u) {
    union { unsigned int i; float f; } v; v.i = ((unsigned int)u) << 16; return v.f;
}
__device__ __forceinline__ unsigned short f2b(float f) {
    __hip_bfloat16 hb = __float2bfloat16(f);
    return *(unsigned short*)&hb;
}
__device__ __forceinline__ float ldin(const void* p, int idx, int isf32) {
    return isf32 ? ((const float*)p)[idx] : u2f(((const unsigned short*)p)[idx]);
}
__device__ __forceinline__ int get_tpred(const int* p) {
    int v = p[0];
    if (v >= 0 && v <= 64) return v;
    float f = ((const float*)p)[0];
    if (f >= 0.f && f <= 64.f) return (int)f;
    float g = u2f(((const unsigned short*)p)[0]);
    if (g >= 0.f && g <= 64.f) return (int)g;
    return 31;
}

// ---------------- dtype detector: bf16-decode W_soc, look for huge/NaN -----
__global__ __launch_bounds__(256) void k_detect(const void* __restrict__ Wsoc,
                                                int* __restrict__ flag) {
    __shared__ int f;
    int tid = threadIdx.x;
    if (tid == 0) f = 0;
    __syncthreads();
    const unsigned short* p = (const unsigned short*)Wsoc;
    #pragma unroll
    for (int k = 0; k < 4; k++) {
        float v = u2f(p[tid * 4 + k]);
        if (!(v == v) || fabsf(v) > 1e20f) f = 1;   // same-address LDS write, benign
    }
    __syncthreads();
    if (tid == 0) flag[0] = f;
}

// ---------------- one-time: W_soc (4096x256) -> Wt bf16 (256x4096) ---------
__global__ __launch_bounds__(256) void k_transpose(const void* __restrict__ Wsoc,
                                                   unsigned short* __restrict__ Wt,
                                                   const int* __restrict__ flag) {
    __shared__ __align__(16) unsigned short tile[32 * 264];
    int isf32 = flag[0];
    int b = blockIdx.x, tid = threadIdx.x;
    int k0 = b * 32;
    if (isf32) {
        const float* W = (const float*)Wsoc;
        #pragma unroll
        for (int p = 0; p < 4; p++) {
            int kk = (tid >> 5) + p * 8;
            int n8 = (tid & 31) * 8;
            #pragma unroll
            for (int q = 0; q < 8; q++)
                tile[kk * 264 + n8 + q] = f2b(W[(k0 + kk) * 256 + n8 + q]);
        }
    } else {
        const unsigned short* W = (const unsigned short*)Wsoc;
        #pragma unroll
        for (int p = 0; p < 4; p++) {
            int kk = (tid >> 5) + p * 8;
            int n8 = (tid & 31) * 8;
            *(uint4*)&tile[kk * 264 + n8] = *(const uint4*)(W + (k0 + kk) * 256 + n8);
        }
    }
    __syncthreads();
    int n = tid;
    unsigned int packed[16];
    #pragma unroll
    for (int q = 0; q < 16; q++) {
        unsigned int lo = tile[(2 * q) * 264 + n];
        unsigned int hi = tile[(2 * q + 1) * 264 + n];
        packed[q] = lo | (hi << 16);
    }
    uint4* dst = (uint4*)(Wt + (long)n * 4096 + k0);
    #pragma unroll
    for (int p = 0; p < 4; p++)
        dst[p] = make_uint4(packed[4*p], packed[4*p+1], packed[4*p+2], packed[4*p+3]);
}

// ---------------- one-time: zero d_out (dtype-sized), h0/c0 -> f32 ---------
__global__ __launch_bounds__(256) void k_init(void* __restrict__ out,
                                              const void* __restrict__ hin,
                                              const void* __restrict__ cin,
                                              float* __restrict__ h_ws,
                                              float* __restrict__ c_ws,
                                              const int* __restrict__ flag) {
    int isf32 = flag[0];
    int b = blockIdx.x, tid = threadIdx.x;
    if (b < 16) {
        uint4 z = make_uint4(0u, 0u, 0u, 0u);
        uint4* p = (uint4*)out;
        int n16 = isf32 ? 16384 : 8192;          // 65536 elems * 4 or 2 bytes / 16
        for (int idx = b * 256 + tid; idx < n16; idx += 4096) p[idx] = z;
    } else {
        int sb = b - 16;
        const void* src = (sb < 16) ? hin : cin;
        float* dst = (sb < 16) ? h_ws : c_ws;
        sb &= 15;
        int base = (sb * 256 + tid) * 16;
        #pragma unroll
        for (int p = 0; p < 16; p++) dst[base + p] = ldin(src, base + p, isf32);
    }
}

// ---------------- per step: social pooling -> Hbuf, epre=b_soc, r ----------
// Per block: agent i. Codes lane-parallel; per wave, ballot-compacted j-lists
// per cell; register accumulation with 4-deep load pipelining; one store/cell.
__global__ __launch_bounds__(256) void k_pool(const void* __restrict__ X,
                                              const int* __restrict__ masks,
                                              const void* __restrict__ bsoc,
                                              const void* __restrict__ Wemb,
                                              const void* __restrict__ bemb,
                                              const int* __restrict__ Tpred,
                                              const int* __restrict__ flag,
                                              const float* __restrict__ h_ws,
                                              float* __restrict__ r_ws,
                                              float* __restrict__ epre,
                                              unsigned short* __restrict__ Hbuf,
                                              int t) {
    if (t > get_tpred(Tpred)) return;
    int isf32 = flag[0];
    int i = blockIdx.x, tid = threadIdx.x;
    __shared__ unsigned char code[1024];
    __shared__ unsigned short jl[4][1024];
    int mi = masks[t * 1024 + i];
    float cix, ciy;
    if (isf32) {
        const float* Xf = (const float*)X;
        cix = Xf[(t * 1024 + i) * 4 + 2];
        ciy = Xf[(t * 1024 + i) * 4 + 3];
    } else {
        const unsigned short* Xb = (const unsigned short*)X;
        cix = u2f(Xb[(t * 1024 + i) * 4 + 2]);
        ciy = u2f(Xb[(t * 1024 + i) * 4 + 3]);
    }
    epre[i * 256 + tid] = ldin(bsoc, tid, isf32);
    if (tid < 64) {
        float v = ldin(Wemb, tid, isf32) * cix + ldin(Wemb, 64 + tid, isf32) * ciy
                + ldin(bemb, tid, isf32);
        r_ws[i * 64 + tid] = fmaxf(v, 0.f);
    }
    if (mi != 0) {
        #pragma unroll
        for (int p = 0; p < 4; p++) {
            int j = tid + p * 256;
            unsigned char cc = 0xFF;
            if (j != i && masks[t * 1024 + j] != 0) {
                float dx, dy;
                if (isf32) {
                    const float* Xf = (const float*)X;
                    dx = Xf[(t * 1024 + j) * 4 + 2] - cix;
                    dy = Xf[(t * 1024 + j) * 4 + 3] - ciy;
                } else {
                    const unsigned short* Xb = (const unsigned short*)X;
                    dx = u2f(Xb[(t * 1024 + j) * 4 + 2]) - cix;
                    dy = u2f(Xb[(t * 1024 + j) * 4 + 3]) - ciy;
                }
                int g0 = (int)dx, g1 = (int)dy;   // trunc toward zero == jnp.trunc
                if (g0 >= -3 && g0 <= 3 && g1 >= -3 && g1 <= 3)
                    cc = (unsigned char)((g0 + 3) * 7 + (g1 + 3));   // dense 0..48
            }
            code[j] = cc;
        }
    }
    __syncthreads();
    int w = tid >> 6, lane = tid & 63;
    long hb_base = (long)i * 3136;
    if (mi == 0) {   // block-uniform: H row is all zeros
        unsigned int* hp = (unsigned int*)(Hbuf + hb_base);
        for (int idx = tid; idx < 1568; idx += 256) hp[idx] = 0u;
        return;
    }
    unsigned int creg[16];
    #pragma unroll
    for (int ch = 0; ch < 16; ch++) creg[ch] = code[ch * 64 + lane];
    unsigned short* wl = jl[w];
    for (int c = w; c < 49; c += 4) {       // round-robin cells over 4 waves
        int n = 0;
        #pragma unroll
        for (int ch = 0; ch < 16; ch++) {
            bool p = (creg[ch] == (unsigned int)c);
            unsigned long long m = __ballot(p);
            if (p) {
                int rank = __popcll(m & ((1ull << lane) - 1ull));
                wl[n + rank] = (unsigned short)(ch * 64 + lane);
            }
            n += (int)__popcll(m);
        }
        float acc = 0.f;
        int k = 0;
        for (; k + 4 <= n; k += 4) {        // 4 loads in flight per group
            int j0 = wl[k], j1 = wl[k + 1], j2 = wl[k + 2], j3 = wl[k + 3];
            float v0 = h_ws[j0 * 64 + lane];
            float v1 = h_ws[j1 * 64 + lane];
            float v2 = h_ws[j2 * 64 + lane];
            float v3 = h_ws[j3 * 64 + lane];
            acc += (v0 + v1) + (v2 + v3);
        }
        for (; k < n; k++) acc += h_ws[wl[k] * 64 + lane];
        Hbuf[hb_base + c * 64 + lane] = f2b(acc);
    }
}

// ---------------- per step: epre += H @ W_soc (MFMA, K-split atomics) ------
__global__ __launch_bounds__(256) void k_gemm(const unsigned short* __restrict__ Hbuf,
                                              const unsigned short* __restrict__ Wt,
                                              const int* __restrict__ Tpred,
                                              float* __restrict__ epre,
                                              int t) {
    if (t > get_tpred(Tpred)) return;
    int bid = blockIdx.x, tid = threadIdx.x;
    int s = bid & 15, rb = bid >> 4;
    int row0 = rb * 64;
    int m0 = 3 * s, m1 = (s == 15) ? 49 : (3 * s + 3);   // 49 used cells
    __shared__ __align__(16) short Asm[64 * 72];   // 64 rows x 64 k, stride 72
    __shared__ __align__(16) short Bsm[256 * 72];  // 256 n x 64 k, stride 72
    int w = tid >> 6, lane = tid & 63;
    int wrow = (w & 1) * 32, wcol = (w >> 1) * 128;
    int mrow = lane & 15, q = lane >> 4;
    f32x4 acc[2][8];
    f32x4 zz = {0.f, 0.f, 0.f, 0.f};
    #pragma unroll
    for (int a = 0; a < 2; a++)
        #pragma unroll
        for (int b = 0; b < 8; b++) acc[a][b] = zz;
    for (int m = m0; m < m1; m++) {
        int wcell = ((m / 7) * 8 + (m % 7) + 9) * 64;   // column base in Wt
        __syncthreads();
        {
            int row = tid >> 2;
            #pragma unroll
            for (int p = 0; p < 2; p++) {
                int seg = (tid & 3) + (p << 2);
                *(uint4*)&Asm[row * 72 + seg * 8] =
                    *(const uint4*)(Hbuf + (long)(row0 + row) * 3136 + m * 64 + seg * 8);
            }
            #pragma unroll
            for (int p = 0; p < 8; p++) {
                *(uint4*)&Bsm[tid * 72 + p * 8] =
                    *(const uint4*)(Wt + (long)tid * 4096 + wcell + p * 8);
            }
        }
        __syncthreads();
        #pragma unroll
        for (int kc = 0; kc < 2; kc++) {
            bf16x8 a0 = *(bf16x8*)&Asm[(wrow +      mrow) * 72 + kc * 32 + q * 8];
            bf16x8 a1 = *(bf16x8*)&Asm[(wrow + 16 + mrow) * 72 + kc * 32 + q * 8];
            #pragma unroll
            for (int ct = 0; ct < 8; ct++) {
                bf16x8 bv = *(bf16x8*)&Bsm[(wcol + ct * 16 + mrow) * 72 + kc * 32 + q * 8];
                acc[0][ct] = __builtin_amdgcn_mfma_f32_16x16x32_bf16(a0, bv, acc[0][ct], 0, 0, 0);
                acc[1][ct] = __builtin_amdgcn_mfma_f32_16x16x32_bf16(a1, bv, acc[1][ct], 0, 0, 0);
            }
        }
    }
    // C/D layout: col = lane&15, row = (lane>>4)*4 + reg
    #pragma unroll
    for (int rt = 0; rt < 2; rt++)
        #pragma unroll
        for (int ct = 0; ct < 8; ct++)
            #pragma unroll
            for (int r = 0; r < 4; r++) {
                int grow = row0 + wrow + rt * 16 + q * 4 + r;
                int gcol = wcol + ct * 16 + mrow;
                atomicAdd(&epre[grow * 256 + gcol], acc[rt][ct][r]);
            }
}

// ---------------- per step: gates, LSTM cell, output -----------------------
__global__ __launch_bounds__(256) void k_cell(const int* __restrict__ masks,
                                              const void* __restrict__ Y,
                                              const void* __restrict__ Wih,
                                              const void* __restrict__ bih,
                                              const void* __restrict__ Whh,
                                              const void* __restrict__ bhh,
                                              const void* __restrict__ Wout,
                                              const void* __restrict__ bout,
                                              const int* __restrict__ Tpred,
                                              const int* __restrict__ flag,
                                              float* __restrict__ h_ws,
                                              float* __restrict__ c_ws,
                                              const float* __restrict__ r_ws,
                                              const float* __restrict__ epre,
                                              void* __restrict__ out,
                                              int t) {
    if (t > get_tpred(Tpred)) return;
    int isf32 = flag[0];
    int tid = threadIdx.x;
    int half = tid >> 7;
    int row = blockIdx.x * 2 + half;
    int tt = tid & 127;
    int s = tt >> 6, lane = tt & 63;
    __shared__ float z[2][384];
    __shared__ float gacc[2][256];
    for (int idx = tt; idx < 384; idx += 128) {
        float v;
        if (idx < 64)       v = r_ws[row * 64 + idx];
        else if (idx < 320) v = fmaxf(epre[row * 256 + (idx - 64)], 0.f);
        else                v = h_ws[row * 64 + (idx - 320)];
        z[half][idx] = v;
    }
    __syncthreads();
    float a0 = 0.f, a1 = 0.f, a2 = 0.f, a3 = 0.f;
    int kk0 = s * 192;
    if (isf32) {
        const float* WihF = (const float*)Wih;
        const float* WhhF = (const float*)Whh;
        for (int kk = kk0; kk < kk0 + 192; kk++) {
            float zv = z[half][kk];
            const float* Wr = (kk < 320) ? (WihF + (long)kk * 256)
                                         : (WhhF + (long)(kk - 320) * 256);
            a0 += zv * Wr[lane];
            a1 += zv * Wr[64 + lane];
            a2 += zv * Wr[128 + lane];
            a3 += zv * Wr[192 + lane];
        }
    } else {
        const unsigned short* WihB = (const unsigned short*)Wih;
        const unsigned short* WhhB = (const unsigned short*)Whh;
        for (int kk = kk0; kk < kk0 + 192; kk++) {
            float zv = z[half][kk];
            const unsigned short* Wr = (kk < 320) ? (WihB + (long)kk * 256)
                                                  : (WhhB + (long)(kk - 320) * 256);
            a0 += zv * u2f(Wr[lane]);
            a1 += zv * u2f(Wr[64 + lane]);
            a2 += zv * u2f(Wr[128 + lane]);
            a3 += zv * u2f(Wr[192 + lane]);
        }
    }
    if (s == 0) {
        gacc[half][lane] = a0; gacc[half][64 + lane] = a1;
        gacc[half][128 + lane] = a2; gacc[half][192 + lane] = a3;
    }
    __syncthreads();
    if (s == 1) {
        float gi = a0 + gacc[half][lane]       + ldin(bih, lane, isf32)       + ldin(bhh, lane, isf32);
        float gf = a1 + gacc[half][64 + lane]  + ldin(bih, 64 + lane, isf32)  + ldin(bhh, 64 + lane, isf32);
        float gg = a2 + gacc[half][128 + lane] + ldin(bih, 128 + lane, isf32) + ldin(bhh, 128 + lane, isf32);
        float go = a3 + gacc[half][192 + lane] + ldin(bih, 192 + lane, isf32) + ldin(bhh, 192 + lane, isf32);
        float c  = c_ws[row * 64 + lane];
        float si = 1.f / (1.f + __expf(-gi));
        float sf = 1.f / (1.f + __expf(-gf));
        float so = 1.f / (1.f + __expf(-go));
        float cn = sf * c + si * tanhf(gg);
        float hn = so * tanhf(cn);
        c_ws[row * 64 + lane] = cn;
        h_ws[row * 64 + lane] = hn;
        float p0 = hn * ldin(Wout, lane * 2 + 0, isf32);
        float p1 = hn * ldin(Wout, lane * 2 + 1, isf32);
        #pragma unroll
        for (int o = 32; o >= 1; o >>= 1) {
            p0 += __shfl_xor(p0, o);
            p1 += __shfl_xor(p1, o);
        }
        if (lane == 0) {
            int m = masks[t * 1024 + row];
            float o0 = 0.f, o1 = 0.f;
            if (m != 0) {
                bool appear = (t > 3) && (masks[(t - 3) * 1024 + row] == 0);
                if (appear) {
                    o0 = ldin(Y, (t * 1024 + row) * 2 + 0, isf32);
                    o1 = ldin(Y, (t * 1024 + row) * 2 + 1, isf32);
                } else {
                    o0 = p0 + ldin(bout, 0, isf32);
                    o1 = p1 + ldin(bout, 1, isf32);
                }
            }
            if (!(o0 == o0)) o0 = 0.f;            // sanitize: finite diagnostics
            if (!(o1 == o1)) o1 = 0.f;
            int ofs = (t * 1024 + row) * 2;
            if (isf32) {
                ((float*)out)[ofs + 0] = o0;
                ((float*)out)[ofs + 1] = o1;
            } else {
                ((unsigned short*)out)[ofs + 0] = f2b(o0);
                ((unsigned short*)out)[ofs + 1] = f2b(o1);
            }
        }
    }
}

extern "C" void kernel_launch(void* const* d_in, const int* in_sizes, int n_in,
                              void* d_out, int out_size, void* d_ws, size_t ws_size,
                              hipStream_t stream) {
    (void)in_sizes; (void)n_in; (void)out_size; (void)ws_size;
    const void* X     = d_in[0];
    const int*  masks = (const int*)d_in[1];
    const void* h0    = d_in[2];
    const void* c0    = d_in[3];
    const void* Y     = d_in[4];
    // d_in[5] = T_obs (unused by reference)
    const int*  Tpred = (const int*)d_in[6];
    const void* Wemb  = d_in[7];
    const void* bemb  = d_in[8];
    const void* Wsoc  = d_in[9];
    const void* bsoc  = d_in[10];
    const void* Wih   = d_in[11];
    const void* bih   = d_in[12];
    const void* Whh   = d_in[13];
    const void* bhh   = d_in[14];
    const void* Wout  = d_in[15];
    const void* bout  = d_in[16];

    char* ws = (char*)d_ws;
    float*          h_ws = (float*)(ws + 0);
    float*          c_ws = (float*)(ws + 262144);
    float*          r_ws = (float*)(ws + 524288);
    float*          epre = (float*)(ws + 786432);
    unsigned short* Wt   = (unsigned short*)(ws + 1835008);
    unsigned short* Hbuf = (unsigned short*)(ws + 3932160);
    int*            flag = (int*)(ws + 11141120);

    k_detect<<<1, 256, 0, stream>>>(Wsoc, flag);
    k_transpose<<<128, 256, 0, stream>>>(Wsoc, Wt, flag);
    k_init<<<48, 256, 0, stream>>>(d_out, h0, c0, h_ws, c_ws, flag);
    for (int t = 0; t < 32; t++) {
        k_pool<<<1024, 256, 0, stream>>>(X, masks, bsoc, Wemb, bemb, Tpred, flag,
                                         h_ws, r_ws, epre, Hbuf, t);
        k_gemm<<<256, 256, 0, stream>>>(Hbuf, Wt, Tpred, epre, t);
        k_cell<<<512, 256, 0, stream>>>(masks, Y, Wih, bih, Whh, bhh, Wout, bout,
                                        Tpred, flag, h_ws, c_ws, r_ws, epre, d_out, t);
    }
}

// Round 4
// 1547.618 us; speedup vs baseline: 1.8924x; 1.1172x over previous
//
#include <hip/hip_runtime.h>
#include <hip/hip_bf16.h>

// SocialLSTM forward, MI355X gfx950.
// Dual-dtype: float inputs may be bf16 or f32; detected at runtime from W_soc.
// ws layout (bytes):
//   h_ws  f32[1024*64]    @ 0
//   c_ws  f32[1024*64]    @ 262144
//   r_ws  f32[1024*64]    @ 524288
//   (free)                @ 786432
//   Wt    bf16[256*4096]  @ 1835008   (W_soc transposed, [n][k])
//   Hbuf  bf16[1024*3136] @ 3932160   (49 reachable cells * 64 hid per row)
//   flag  int32           @ 11141120  (0 = bf16 inputs, 1 = f32 inputs)
//   part  f32[16][1024*256] @ 16777216  (K-split GEMM partials, no atomics)

typedef short bf16x8 __attribute__((ext_vector_type(8)));
typedef float f32x4 __attribute__((ext_vector_type(4)));

__device__ __forceinline__ float u2f(unsigned short u) {
    union { unsigned int i; float f; } v; v.i = ((unsigned int)u) << 16; return v.f;
}
__device__ __forceinline__ unsigned short f2b(float f) {
    __hip_bfloat16 hb = __float2bfloat16(f);
    return *(unsigned short*)&hb;
}
__device__ __forceinline__ float ldin(const void* p, int idx, int isf32) {
    return isf32 ? ((const float*)p)[idx] : u2f(((const unsigned short*)p)[idx]);
}
__device__ __forceinline__ int get_tpred(const int* p) {
    int v = p[0];
    if (v >= 0 && v <= 64) return v;
    float f = ((const float*)p)[0];
    if (f >= 0.f && f <= 64.f) return (int)f;
    float g = u2f(((const unsigned short*)p)[0]);
    if (g >= 0.f && g <= 64.f) return (int)g;
    return 31;
}

// ---------------- dtype detector: bf16-decode W_soc, look for huge/NaN -----
__global__ __launch_bounds__(256) void k_detect(const void* __restrict__ Wsoc,
                                                int* __restrict__ flag) {
    __shared__ int f;
    int tid = threadIdx.x;
    if (tid == 0) f = 0;
    __syncthreads();
    const unsigned short* p = (const unsigned short*)Wsoc;
    #pragma unroll
    for (int k = 0; k < 4; k++) {
        float v = u2f(p[tid * 4 + k]);
        if (!(v == v) || fabsf(v) > 1e20f) f = 1;   // same-address LDS write, benign
    }
    __syncthreads();
    if (tid == 0) flag[0] = f;
}

// ---------------- one-time: W_soc (4096x256) -> Wt bf16 (256x4096) ---------
__global__ __launch_bounds__(256) void k_transpose(const void* __restrict__ Wsoc,
                                                   unsigned short* __restrict__ Wt,
                                                   const int* __restrict__ flag) {
    __shared__ __align__(16) unsigned short tile[32 * 264];
    int isf32 = flag[0];
    int b = blockIdx.x, tid = threadIdx.x;
    int k0 = b * 32;
    if (isf32) {
        const float* W = (const float*)Wsoc;
        #pragma unroll
        for (int p = 0; p < 4; p++) {
            int kk = (tid >> 5) + p * 8;
            int n8 = (tid & 31) * 8;
            #pragma unroll
            for (int q = 0; q < 8; q++)
                tile[kk * 264 + n8 + q] = f2b(W[(k0 + kk) * 256 + n8 + q]);
        }
    } else {
        const unsigned short* W = (const unsigned short*)Wsoc;
        #pragma unroll
        for (int p = 0; p < 4; p++) {
            int kk = (tid >> 5) + p * 8;
            int n8 = (tid & 31) * 8;
            *(uint4*)&tile[kk * 264 + n8] = *(const uint4*)(W + (k0 + kk) * 256 + n8);
        }
    }
    __syncthreads();
    int n = tid;
    unsigned int packed[16];
    #pragma unroll
    for (int q = 0; q < 16; q++) {
        unsigned int lo = tile[(2 * q) * 264 + n];
        unsigned int hi = tile[(2 * q + 1) * 264 + n];
        packed[q] = lo | (hi << 16);
    }
    uint4* dst = (uint4*)(Wt + (long)n * 4096 + k0);
    #pragma unroll
    for (int p = 0; p < 4; p++)
        dst[p] = make_uint4(packed[4*p], packed[4*p+1], packed[4*p+2], packed[4*p+3]);
}

// ---------------- one-time: zero d_out (dtype-sized), h0/c0 -> f32 ---------
__global__ __launch_bounds__(256) void k_init(void* __restrict__ out,
                                              const void* __restrict__ hin,
                                              const void* __restrict__ cin,
                                              float* __restrict__ h_ws,
                                              float* __restrict__ c_ws,
                                              const int* __restrict__ flag) {
    int isf32 = flag[0];
    int b = blockIdx.x, tid = threadIdx.x;
    if (b < 16) {
        uint4 z = make_uint4(0u, 0u, 0u, 0u);
        uint4* p = (uint4*)out;
        int n16 = isf32 ? 16384 : 8192;          // 65536 elems * 4 or 2 bytes / 16
        for (int idx = b * 256 + tid; idx < n16; idx += 4096) p[idx] = z;
    } else {
        int sb = b - 16;
        const void* src = (sb < 16) ? hin : cin;
        float* dst = (sb < 16) ? h_ws : c_ws;
        sb &= 15;
        int base = (sb * 256 + tid) * 16;
        #pragma unroll
        for (int p = 0; p < 16; p++) dst[base + p] = ldin(src, base + p, isf32);
    }
}

// ---------------- per step: social pooling -> Hbuf, r ----------------------
// Per block: agent i. Codes lane-parallel; per wave, ballot-compacted j-lists
// per cell; register accumulation with 8-deep load pipelining; one store/cell.
__global__ __launch_bounds__(256) void k_pool(const void* __restrict__ X,
                                              const int* __restrict__ masks,
                                              const void* __restrict__ Wemb,
                                              const void* __restrict__ bemb,
                                              const int* __restrict__ Tpred,
                                              const int* __restrict__ flag,
                                              const float* __restrict__ h_ws,
                                              float* __restrict__ r_ws,
                                              unsigned short* __restrict__ Hbuf,
                                              int t) {
    if (t > get_tpred(Tpred)) return;
    int isf32 = flag[0];
    int i = blockIdx.x, tid = threadIdx.x;
    __shared__ unsigned char code[1024];
    __shared__ unsigned short jl[4][1024];
    int mi = masks[t * 1024 + i];
    float cix, ciy;
    if (isf32) {
        const float* Xf = (const float*)X;
        cix = Xf[(t * 1024 + i) * 4 + 2];
        ciy = Xf[(t * 1024 + i) * 4 + 3];
    } else {
        const unsigned short* Xb = (const unsigned short*)X;
        cix = u2f(Xb[(t * 1024 + i) * 4 + 2]);
        ciy = u2f(Xb[(t * 1024 + i) * 4 + 3]);
    }
    if (tid < 64) {
        float v = ldin(Wemb, tid, isf32) * cix + ldin(Wemb, 64 + tid, isf32) * ciy
                + ldin(bemb, tid, isf32);
        r_ws[i * 64 + tid] = fmaxf(v, 0.f);
    }
    if (mi != 0) {
        #pragma unroll
        for (int p = 0; p < 4; p++) {
            int j = tid + p * 256;
            unsigned char cc = 0xFF;
            if (j != i && masks[t * 1024 + j] != 0) {
                float dx, dy;
                if (isf32) {
                    const float* Xf = (const float*)X;
                    dx = Xf[(t * 1024 + j) * 4 + 2] - cix;
                    dy = Xf[(t * 1024 + j) * 4 + 3] - ciy;
                } else {
                    const unsigned short* Xb = (const unsigned short*)X;
                    dx = u2f(Xb[(t * 1024 + j) * 4 + 2]) - cix;
                    dy = u2f(Xb[(t * 1024 + j) * 4 + 3]) - ciy;
                }
                int g0 = (int)dx, g1 = (int)dy;   // trunc toward zero == jnp.trunc
                if (g0 >= -3 && g0 <= 3 && g1 >= -3 && g1 <= 3)
                    cc = (unsigned char)((g0 + 3) * 7 + (g1 + 3));   // dense 0..48
            }
            code[j] = cc;
        }
    }
    __syncthreads();
    int w = tid >> 6, lane = tid & 63;
    long hb_base = (long)i * 3136;
    if (mi == 0) {   // block-uniform: H row is all zeros
        unsigned int* hp = (unsigned int*)(Hbuf + hb_base);
        for (int idx = tid; idx < 1568; idx += 256) hp[idx] = 0u;
        return;
    }
    unsigned int creg[16];
    #pragma unroll
    for (int ch = 0; ch < 16; ch++) creg[ch] = code[ch * 64 + lane];
    unsigned short* wl = jl[w];
    for (int c = w; c < 49; c += 4) {       // round-robin cells over 4 waves
        int n = 0;
        #pragma unroll
        for (int ch = 0; ch < 16; ch++) {
            bool p = (creg[ch] == (unsigned int)c);
            unsigned long long m = __ballot(p);
            if (p) {
                int rank = __popcll(m & ((1ull << lane) - 1ull));
                wl[n + rank] = (unsigned short)(ch * 64 + lane);
            }
            n += (int)__popcll(m);
        }
        float acc = 0.f;
        int k = 0;
        for (; k + 8 <= n; k += 8) {        // 8 loads in flight per group
            int j0 = wl[k], j1 = wl[k + 1], j2 = wl[k + 2], j3 = wl[k + 3];
            int j4 = wl[k + 4], j5 = wl[k + 5], j6 = wl[k + 6], j7 = wl[k + 7];
            float v0 = h_ws[j0 * 64 + lane];
            float v1 = h_ws[j1 * 64 + lane];
            float v2 = h_ws[j2 * 64 + lane];
            float v3 = h_ws[j3 * 64 + lane];
            float v4 = h_ws[j4 * 64 + lane];
            float v5 = h_ws[j5 * 64 + lane];
            float v6 = h_ws[j6 * 64 + lane];
            float v7 = h_ws[j7 * 64 + lane];
            acc += ((v0 + v1) + (v2 + v3)) + ((v4 + v5) + (v6 + v7));
        }
        for (; k < n; k++) acc += h_ws[wl[k] * 64 + lane];
        Hbuf[hb_base + c * 64 + lane] = f2b(acc);
    }
}

// ---------------- per step: part[s] = H @ W_soc slice (MFMA, no atomics) ---
// grid 1024: ch = bid&3 (64-col slice), s = (bid>>2)&15 (K-split), rb = bid>>6.
__global__ __launch_bounds__(256) void k_gemm(const unsigned short* __restrict__ Hbuf,
                                              const unsigned short* __restrict__ Wt,
                                              const int* __restrict__ Tpred,
                                              float* __restrict__ part,
                                              int t) {
    if (t > get_tpred(Tpred)) return;
    int bid = blockIdx.x, tid = threadIdx.x;
    int ch = bid & 3, s = (bid >> 2) & 15, rb = bid >> 6;
    int row0 = rb * 64, col0 = ch * 64;
    int m0 = 3 * s, m1 = (s == 15) ? 49 : (3 * s + 3);   // 49 used cells
    __shared__ __align__(16) short Asm[64 * 72];   // 64 rows x 64 k, stride 72
    __shared__ __align__(16) short Bsm[64 * 72];   // 64 n x 64 k, stride 72
    int w = tid >> 6, lane = tid & 63;
    int wrow = (w & 1) * 32, wcol = (w >> 1) * 32;
    int mrow = lane & 15, q = lane >> 4;
    f32x4 acc[2][2];
    f32x4 zz = {0.f, 0.f, 0.f, 0.f};
    #pragma unroll
    for (int a = 0; a < 2; a++)
        #pragma unroll
        for (int b = 0; b < 2; b++) acc[a][b] = zz;
    for (int m = m0; m < m1; m++) {
        int wcell = ((m / 7) * 8 + (m % 7) + 9) * 64;   // column base in Wt
        __syncthreads();
        {
            int row = tid >> 2;
            #pragma unroll
            for (int p = 0; p < 2; p++) {
                int seg = (tid & 3) + (p << 2);
                *(uint4*)&Asm[row * 72 + seg * 8] =
                    *(const uint4*)(Hbuf + (long)(row0 + row) * 3136 + m * 64 + seg * 8);
                *(uint4*)&Bsm[row * 72 + seg * 8] =
                    *(const uint4*)(Wt + (long)(col0 + row) * 4096 + wcell + seg * 8);
            }
        }
        __syncthreads();
        #pragma unroll
        for (int kc = 0; kc < 2; kc++) {
            bf16x8 a0 = *(bf16x8*)&Asm[(wrow +      mrow) * 72 + kc * 32 + q * 8];
            bf16x8 a1 = *(bf16x8*)&Asm[(wrow + 16 + mrow) * 72 + kc * 32 + q * 8];
            #pragma unroll
            for (int ct = 0; ct < 2; ct++) {
                bf16x8 bv = *(bf16x8*)&Bsm[(wcol + ct * 16 + mrow) * 72 + kc * 32 + q * 8];
                acc[0][ct] = __builtin_amdgcn_mfma_f32_16x16x32_bf16(a0, bv, acc[0][ct], 0, 0, 0);
                acc[1][ct] = __builtin_amdgcn_mfma_f32_16x16x32_bf16(a1, bv, acc[1][ct], 0, 0, 0);
            }
        }
    }
    // C/D layout: col = lane&15, row = (lane>>4)*4 + reg. Plain stores, no RMW.
    float* ps = part + (long)s * 262144;
    #pragma unroll
    for (int rt = 0; rt < 2; rt++)
        #pragma unroll
        for (int ct = 0; ct < 2; ct++)
            #pragma unroll
            for (int r = 0; r < 4; r++) {
                int grow = row0 + wrow + rt * 16 + q * 4 + r;
                int gcol = col0 + wcol + ct * 16 + mrow;
                ps[grow * 256 + gcol] = acc[rt][ct][r];
            }
}

// ---------------- per step: 16-way partial reduce, gates, LSTM cell, out ---
__global__ __launch_bounds__(256) void k_cell(const int* __restrict__ masks,
                                              const void* __restrict__ Y,
                                              const void* __restrict__ bsoc,
                                              const void* __restrict__ Wih,
                                              const void* __restrict__ bih,
                                              const void* __restrict__ Whh,
                                              const void* __restrict__ bhh,
                                              const void* __restrict__ Wout,
                                              const void* __restrict__ bout,
                                              const int* __restrict__ Tpred,
                                              const int* __restrict__ flag,
                                              float* __restrict__ h_ws,
                                              float* __restrict__ c_ws,
                                              const float* __restrict__ r_ws,
                                              const float* __restrict__ part,
                                              void* __restrict__ out,
                                              int t) {
    if (t > get_tpred(Tpred)) return;
    int isf32 = flag[0];
    int tid = threadIdx.x;
    int half = tid >> 7;
    int row = blockIdx.x * 2 + half;
    int tt = tid & 127;
    int s = tt >> 6, lane = tt & 63;
    __shared__ float z[2][384];
    __shared__ float gacc[2][256];
    for (int idx = tt; idx < 384; idx += 128) {
        float v;
        if (idx < 64)       v = r_ws[row * 64 + idx];
        else if (idx < 320) {
            int col = idx - 64;
            float e = ldin(bsoc, col, isf32);
            float ps0 = 0.f, ps1 = 0.f, ps2 = 0.f, ps3 = 0.f;
            #pragma unroll
            for (int ss = 0; ss < 4; ss++) {
                ps0 += part[(ss * 4 + 0) * 262144 + row * 256 + col];
                ps1 += part[(ss * 4 + 1) * 262144 + row * 256 + col];
                ps2 += part[(ss * 4 + 2) * 262144 + row * 256 + col];
                ps3 += part[(ss * 4 + 3) * 262144 + row * 256 + col];
            }
            v = fmaxf(e + ((ps0 + ps1) + (ps2 + ps3)), 0.f);
        }
        else                v = h_ws[row * 64 + (idx - 320)];
        z[half][idx] = v;
    }
    __syncthreads();
    float a0 = 0.f, a1 = 0.f, a2 = 0.f, a3 = 0.f;
    int kk0 = s * 192;
    if (isf32) {
        const float* WihF = (const float*)Wih;
        const float* WhhF = (const float*)Whh;
        for (int kk = kk0; kk < kk0 + 192; kk++) {
            float zv = z[half][kk];
            const float* Wr = (kk < 320) ? (WihF + (long)kk * 256)
                                         : (WhhF + (long)(kk - 320) * 256);
            a0 += zv * Wr[lane];
            a1 += zv * Wr[64 + lane];
            a2 += zv * Wr[128 + lane];
            a3 += zv * Wr[192 + lane];
        }
    } else {
        const unsigned short* WihB = (const unsigned short*)Wih;
        const unsigned short* WhhB = (const unsigned short*)Whh;
        for (int kk = kk0; kk < kk0 + 192; kk++) {
            float zv = z[half][kk];
            const unsigned short* Wr = (kk < 320) ? (WihB + (long)kk * 256)
                                                  : (WhhB + (long)(kk - 320) * 256);
            a0 += zv * u2f(Wr[lane]);
            a1 += zv * u2f(Wr[64 + lane]);
            a2 += zv * u2f(Wr[128 + lane]);
            a3 += zv * u2f(Wr[192 + lane]);
        }
    }
    if (s == 0) {
        gacc[half][lane] = a0; gacc[half][64 + lane] = a1;
        gacc[half][128 + lane] = a2; gacc[half][192 + lane] = a3;
    }
    __syncthreads();
    if (s == 1) {
        float gi = a0 + gacc[half][lane]       + ldin(bih, lane, isf32)       + ldin(bhh, lane, isf32);
        float gf = a1 + gacc[half][64 + lane]  + ldin(bih, 64 + lane, isf32)  + ldin(bhh, 64 + lane, isf32);
        float gg = a2 + gacc[half][128 + lane] + ldin(bih, 128 + lane, isf32) + ldin(bhh, 128 + lane, isf32);
        float go = a3 + gacc[half][192 + lane] + ldin(bih, 192 + lane, isf32) + ldin(bhh, 192 + lane, isf32);
        float c  = c_ws[row * 64 + lane];
        float si = 1.f / (1.f + __expf(-gi));
        float sf = 1.f / (1.f + __expf(-gf));
        float so = 1.f / (1.f + __expf(-go));
        float cn = sf * c + si * tanhf(gg);
        float hn = so * tanhf(cn);
        c_ws[row * 64 + lane] = cn;
        h_ws[row * 64 + lane] = hn;
        float p0 = hn * ldin(Wout, lane * 2 + 0, isf32);
        float p1 = hn * ldin(Wout, lane * 2 + 1, isf32);
        #pragma unroll
        for (int o = 32; o >= 1; o >>= 1) {
            p0 += __shfl_xor(p0, o);
            p1 += __shfl_xor(p1, o);
        }
        if (lane == 0) {
            int m = masks[t * 1024 + row];
            float o0 = 0.f, o1 = 0.f;
            if (m != 0) {
                bool appear = (t > 3) && (masks[(t - 3) * 1024 + row] == 0);
                if (appear) {
                    o0 = ldin(Y, (t * 1024 + row) * 2 + 0, isf32);
                    o1 = ldin(Y, (t * 1024 + row) * 2 + 1, isf32);
                } else {
                    o0 = p0 + ldin(bout, 0, isf32);
                    o1 = p1 + ldin(bout, 1, isf32);
                }
            }
            if (!(o0 == o0)) o0 = 0.f;            // sanitize: finite diagnostics
            if (!(o1 == o1)) o1 = 0.f;
            int ofs = (t * 1024 + row) * 2;
            if (isf32) {
                ((float*)out)[ofs + 0] = o0;
                ((float*)out)[ofs + 1] = o1;
            } else {
                ((unsigned short*)out)[ofs + 0] = f2b(o0);
                ((unsigned short*)out)[ofs + 1] = f2b(o1);
            }
        }
    }
}

extern "C" void kernel_launch(void* const* d_in, const int* in_sizes, int n_in,
                              void* d_out, int out_size, void* d_ws, size_t ws_size,
                              hipStream_t stream) {
    (void)in_sizes; (void)n_in; (void)out_size; (void)ws_size;
    const void* X     = d_in[0];
    const int*  masks = (const int*)d_in[1];
    const void* h0    = d_in[2];
    const void* c0    = d_in[3];
    const void* Y     = d_in[4];
    // d_in[5] = T_obs (unused by reference)
    const int*  Tpred = (const int*)d_in[6];
    const void* Wemb  = d_in[7];
    const void* bemb  = d_in[8];
    const void* Wsoc  = d_in[9];
    const void* bsoc  = d_in[10];
    const void* Wih   = d_in[11];
    const void* bih   = d_in[12];
    const void* Whh   = d_in[13];
    const void* bhh   = d_in[14];
    const void* Wout  = d_in[15];
    const void* bout  = d_in[16];

    char* ws = (char*)d_ws;
    float*          h_ws = (float*)(ws + 0);
    float*          c_ws = (float*)(ws + 262144);
    float*          r_ws = (float*)(ws + 524288);
    unsigned short* Wt   = (unsigned short*)(ws + 1835008);
    unsigned short* Hbuf = (unsigned short*)(ws + 3932160);
    int*            flag = (int*)(ws + 11141120);
    float*          part = (float*)(ws + 16777216);

    k_detect<<<1, 256, 0, stream>>>(Wsoc, flag);
    k_transpose<<<128, 256, 0, stream>>>(Wsoc, Wt, flag);
    k_init<<<48, 256, 0, stream>>>(d_out, h0, c0, h_ws, c_ws, flag);
    for (int t = 0; t < 32; t++) {
        k_pool<<<1024, 256, 0, stream>>>(X, masks, Wemb, bemb, Tpred, flag,
                                         h_ws, r_ws, Hbuf, t);
        k_gemm<<<1024, 256, 0, stream>>>(Hbuf, Wt, Tpred, part, t);
        k_cell<<<512, 256, 0, stream>>>(masks, Y, bsoc, Wih, bih, Whh, bhh, Wout, bout,
                                        Tpred, flag, h_ws, c_ws, r_ws, part, d_out, t);
    }
}